// Round 18
// baseline (202.690 us; speedup 1.0000x reference)
//
#include <hip/hip_runtime.h>
#include <math.h>

#define D 4096
#define K 128
#define KP 129          // K+1 (augmented sqrt(EPS)*ones column)
#define NC 144          // padded col count for VbT / Yb (9 tiles of 16; cols >= 129 zero)
#define NROWS 8192
#define QS 144          // Q row stride
#define MS 132          // M row stride
#define NP 132          // padded order for chol
#define NPS 136         // LDS row stride (float4-aligned)
#define NB 12           // panel width (11 panels)
#define NPAN (NP / NB)
#define MSPLIT 3        // T2 accumulation row-split (4 rows/thread); 128+3*120=488<=512
#define NTRACE 45       // 9*10/2 trace tile-pairs
#define LOG2PI 1.8378770664093453

typedef __attribute__((ext_vector_type(8))) short bh8;     // 8 bf16 (4 VGPRs)
typedef __attribute__((ext_vector_type(4))) float f32x4;   // MFMA acc

// ---------------- helpers ----------------
__device__ __forceinline__ unsigned short f2bf(float f) {  // RNE
  unsigned int u = __float_as_uint(f);
  unsigned int r = u + 0x7FFFu + ((u >> 16) & 1u);
  return (unsigned short)(r >> 16);
}
__device__ __forceinline__ float bf2f(unsigned short u) {
  return __uint_as_float(((unsigned int)u) << 16);
}
__device__ __forceinline__ float blo(unsigned int v) { return __uint_as_float(v << 16); }
__device__ __forceinline__ float bhi(unsigned int v) { return __uint_as_float(v & 0xFFFF0000u); }

__device__ __forceinline__ float blockReduceSum256(float v) {
  #pragma unroll
  for (int off = 32; off > 0; off >>= 1) v += __shfl_down(v, off, 64);
  __shared__ float tmp[4];
  __syncthreads();
  if ((threadIdx.x & 63) == 0) tmp[threadIdx.x >> 6] = v;
  __syncthreads();
  float r = 0.0f;
  if (threadIdx.x == 0) r = tmp[0] + tmp[1] + tmp[2] + tmp[3];
  return r;                              // valid on tid 0 only
}

__device__ __forceinline__ float blockReduceSum512(float v) {
  #pragma unroll
  for (int off = 32; off > 0; off >>= 1) v += __shfl_down(v, off, 64);
  __shared__ float tmp8[8];
  __syncthreads();
  if ((threadIdx.x & 63) == 0) tmp8[threadIdx.x >> 6] = v;
  __syncthreads();
  float r = 0.0f;
  if (threadIdx.x == 0) {
    #pragma unroll
    for (int i = 0; i < 8; ++i) r += tmp8[i];
  }
  return r;                              // valid on tid 0 only
}

// ---------------- k_prep: coalesced LDS-transpose + fused mvec ----------------
// VbT[c][d] = bf16( U[d][c] / sigma[d] ); mvec[c] = sum_d bf2f(VbT[c][d]) * mu[d]
#define PD 64                            // d-rows per block
__global__ __launch_bounds__(256) void k_prep(const float* __restrict__ theta,
                                              unsigned short* __restrict__ VbT,
                                              float* __restrict__ mvec) {
  __shared__ float Wt[PD][K + 4];        // transposed W tile
  __shared__ float isg[PD], mul[PD], alp[K];
  int tid = threadIdx.x;
  int d0 = blockIdx.x * PD;
  const float* mu = theta + (size_t)D * K;
  const float* sg = mu + D;
  const float* al = sg + D;

  // coalesced load of W rows d0..d0+63 (64*128 floats = 2048 float4)
  #pragma unroll
  for (int it = 0; it < 8; ++it) {
    int f4 = tid + it * 256;             // 0..2047
    int base = f4 * 4;
    int r = base >> 7, c = base & 127;
    float4 w = *reinterpret_cast<const float4*>(&theta[(size_t)(d0 + r) * K + c]);
    *reinterpret_cast<float4*>(&Wt[r][c]) = w;
  }
  if (tid < PD)            isg[tid] = 1.0f / sg[d0 + tid];
  else if (tid < 2 * PD)   mul[tid - PD] = mu[d0 + tid - PD];
  else                     alp[tid - 128] = al[tid - 128];
  __syncthreads();

  // 9 passes of 16 columns; 16 threads per column, 4 d-values per thread
  int cl = tid >> 4;                     // 0..15 within pass
  int dl = (tid & 15) * 4;
  for (int pc = 0; pc < 9; ++pc) {
    int c = pc * 16 + cl;
    float v0, v1, v2, v3;
    if (c < K) {
      float a = alp[c];
      v0 = Wt[dl + 0][c] * a * isg[dl + 0];
      v1 = Wt[dl + 1][c] * a * isg[dl + 1];
      v2 = Wt[dl + 2][c] * a * isg[dl + 2];
      v3 = Wt[dl + 3][c] * a * isg[dl + 3];
    } else if (c == K) {
      v0 = 1.0e-3f * isg[dl + 0];
      v1 = 1.0e-3f * isg[dl + 1];
      v2 = 1.0e-3f * isg[dl + 2];
      v3 = 1.0e-3f * isg[dl + 3];
    } else {
      v0 = v1 = v2 = v3 = 0.0f;
    }
    ushort4 w;
    w.x = f2bf(v0); w.y = f2bf(v1); w.z = f2bf(v2); w.w = f2bf(v3);
    *reinterpret_cast<ushort4*>(&VbT[(size_t)c * D + d0 + dl]) = w;
    if (c <= K) {
      float mv = bf2f(w.x) * mul[dl + 0] + bf2f(w.y) * mul[dl + 1]
               + bf2f(w.z) * mul[dl + 2] + bf2f(w.w) * mul[dl + 3];
      #pragma unroll
      for (int o = 8; o > 0; o >>= 1) mv += __shfl_xor(mv, o, 16);
      if ((tid & 15) == 0) atomicAdd(&mvec[c], mv);
    }
  }
}

// ---------------- M = I + sum_d sigma_d VbT[j][d] VbT[k][d] ----------------
__global__ __launch_bounds__(256) void k_M(const float* __restrict__ theta,
                                           const unsigned short* __restrict__ VbT,
                                           float* __restrict__ M) {
  int j = blockIdx.x, kk2 = blockIdx.y;
  if (kk2 < j) return;                   // symmetry
  const float* sg = theta + (size_t)D * K + D;
  float acc = 0.0f;
  for (int d0 = threadIdx.x * 8; d0 < D; d0 += 2048) {
    uint4 ua = *reinterpret_cast<const uint4*>(&VbT[(size_t)j * D + d0]);
    uint4 ub = *reinterpret_cast<const uint4*>(&VbT[(size_t)kk2 * D + d0]);
    float4 s0 = *reinterpret_cast<const float4*>(&sg[d0]);
    float4 s1 = *reinterpret_cast<const float4*>(&sg[d0 + 4]);
    acc += s0.x * blo(ua.x) * blo(ub.x) + s0.y * bhi(ua.x) * bhi(ub.x)
         + s0.z * blo(ua.y) * blo(ub.y) + s0.w * bhi(ua.y) * bhi(ub.y)
         + s1.x * blo(ua.z) * blo(ub.z) + s1.y * bhi(ua.z) * bhi(ub.z)
         + s1.z * blo(ua.w) * blo(ub.w) + s1.w * bhi(ua.w) * bhi(ub.w);
  }
  float r = blockReduceSum256(acc);
  if (threadIdx.x == 0) {
    float m = r + (j == kk2 ? 1.0f : 0.0f);
    M[j * MS + kk2] = m;
    M[kk2 * MS + j] = m;
  }
}

// ================= fused parallel kernel (512 threads/block) =================
// block 0: chol | 1..256: gemm(+tvec) | 257..288: colstats(term1,sumlog)
#define GBM 32
#define GBK 128
#define NSTEP (D / GBK)     // 32
#define XSS 136             // LDS row stride in shorts
#define GEMM_BLOCKS (NROWS / GBM)   // 256
#define CS_BLOCKS 32
#define CS_ROWS (NROWS / CS_BLOCKS) // 256

struct CholSh {
  float A[NP][NPS];
  float GT[NP][NPS];       // GT[col][row] = G[row][col] = L^-1 transposed
  float Tst[NPAN][NB][NB + 1];
};
struct GemmSh {
  unsigned short Xs[GBM][XSS];
  unsigned short Vs[NC][XSS];
};
union ParSh {
  CholSh c;
  GemmSh g;
};

__device__ void chol_body(CholSh& sh, const float* __restrict__ Mg,
                          float* __restrict__ Gg, float* __restrict__ scalars) {
  auto& A = sh.A;
  auto& GT = sh.GT;
  auto& Tst = sh.Tst;
  __shared__ float redB[8];
  int tid = threadIdx.x;

  for (int idx = tid; idx < NP * NP; idx += 512) {
    int r = idx / NP, c = idx - r * NP;
    A[r][c] = (r < KP && c < KP) ? Mg[r * MS + c] : (r == c ? 1.0f : 0.0f);
  }
  // zero GT fully (upper blocks are read by full-range dots in k_trace)
  {
    float* gt = &GT[0][0];
    for (int idx = tid; idx < NP * NPS; idx += 512) gt[idx] = 0.0f;
  }
  __syncthreads();

  // ---- blocked Cholesky with fused triangular inverse; G stored TRANSPOSED ----
  for (int p = 0; p < NPAN; ++p) {
    int j0 = p * NB, j1 = j0 + NB;
    int nbrows = NP - j1;
    int nG = p * NB;                     // threads doing G-apply in phase 2
    if (tid < 128) {
      float T[NB][NB];
      #pragma unroll
      for (int r = 0; r < NB; ++r)
        #pragma unroll
        for (int c = 0; c <= r; ++c)
          T[r][c] = A[j0 + r][j0 + c];
      float dinv[NB];
      #pragma unroll
      for (int jj = 0; jj < NB; ++jj) {
        float dv = sqrtf(T[jj][jj]);
        float iv = 1.0f / dv;
        dinv[jj] = iv;
        #pragma unroll
        for (int r = jj + 1; r < NB; ++r) T[r][jj] *= iv;
        #pragma unroll
        for (int cc = jj + 1; cc < NB; ++cc)
          #pragma unroll
          for (int r = cc; r < NB; ++r)
            T[r][cc] -= T[r][jj] * T[cc][jj];
      }
      #pragma unroll
      for (int r = 0; r < NB; ++r) {     // in-place row-wise inverse -> G_pp
        float tmp[NB];
        #pragma unroll
        for (int c = 0; c < r; ++c) {
          float s = 0.0f;
          #pragma unroll
          for (int k = c; k < r; ++k) s += T[r][k] * T[k][c];
          tmp[c] = -s * dinv[r];
        }
        #pragma unroll
        for (int c = 0; c < r; ++c) T[r][c] = tmp[c];
        T[r][r] = dinv[r];
      }
      if (tid == 0) {                    // stash G_pp TRANSPOSED: GT[j0+c][j0+r] = T[r][c]
        #pragma unroll
        for (int c = 0; c < NB; ++c) {
          float g[NB];
          #pragma unroll
          for (int r = 0; r < NB; ++r) g[r] = (r >= c) ? T[r][c] : 0.0f;
          float4* dst = reinterpret_cast<float4*>(&GT[j0 + c][j0]);
          float4 g0 = {g[0], g[1], g[2], g[3]};
          float4 g1 = {g[4], g[5], g[6], g[7]};
          float4 g2 = {g[8], g[9], g[10], g[11]};
          dst[0] = g0; dst[1] = g1; dst[2] = g2;
        }
      }
      if (tid < nbrows) {                // fused panel solve, G_pp from registers
        int r = j1 + tid;
        float* arow = &A[r][j0];
        float4 q0 = *reinterpret_cast<const float4*>(arow);
        float4 q1 = *reinterpret_cast<const float4*>(arow + 4);
        float4 q2 = *reinterpret_cast<const float4*>(arow + 8);
        float ro[NB] = {q0.x, q0.y, q0.z, q0.w, q1.x, q1.y, q1.z, q1.w,
                        q2.x, q2.y, q2.z, q2.w};
        float rn[NB];
        #pragma unroll
        for (int cc = 0; cc < NB; ++cc) {
          float s = 0.0f;
          #pragma unroll
          for (int k = 0; k <= cc; ++k) s += ro[k] * T[cc][k];
          rn[cc] = s;
        }
        float4 w0 = {rn[0], rn[1], rn[2], rn[3]};
        float4 w1 = {rn[4], rn[5], rn[6], rn[7]};
        float4 w2 = {rn[8], rn[9], rn[10], rn[11]};
        *reinterpret_cast<float4*>(arow) = w0;
        *reinterpret_cast<float4*>(arow + 4) = w1;
        *reinterpret_cast<float4*>(arow + 8) = w2;
      }
    } else if (tid < 128 + MSPLIT * nG) {
      // T2[m] = sum_{k=q..p-1} <A[j0+m][kI..], GT[qI+j][kI..]> (float4 dots)
      int t2 = tid - 128;
      int q = t2 / (NB * MSPLIT);
      int rem = t2 - q * (NB * MSPLIT);
      int j = rem % NB, mg = rem / NB;   // mg in 0..2
      int qI = q * NB;
      int m0 = mg * 4;
      float t0 = 0.0f, t1 = 0.0f, t2a = 0.0f, t3 = 0.0f;
      for (int k = q; k < p; ++k) {
        int kI = k * NB;
        const float* gp = &GT[qI + j][kI];
        float4 g0 = *reinterpret_cast<const float4*>(gp);
        float4 g1 = *reinterpret_cast<const float4*>(gp + 4);
        float4 g2 = *reinterpret_cast<const float4*>(gp + 8);
        #pragma unroll
        for (int i = 0; i < 4; ++i) {
          const float* ap = &A[j0 + m0 + i][kI];
          float4 a0 = *reinterpret_cast<const float4*>(ap);
          float4 a1 = *reinterpret_cast<const float4*>(ap + 4);
          float4 a2 = *reinterpret_cast<const float4*>(ap + 8);
          float s = a0.x * g0.x + a0.y * g0.y + a0.z * g0.z + a0.w * g0.w
                  + a1.x * g1.x + a1.y * g1.y + a1.z * g1.z + a1.w * g1.w
                  + a2.x * g2.x + a2.y * g2.y + a2.z * g2.z + a2.w * g2.w;
          if (i == 0) t0 += s;
          else if (i == 1) t1 += s;
          else if (i == 2) t2a += s;
          else t3 += s;
        }
      }
      Tst[q][m0 + 0][j] = t0;
      Tst[q][m0 + 1][j] = t1;
      Tst[q][m0 + 2][j] = t2a;
      Tst[q][m0 + 3][j] = t3;
    }
    __syncthreads();
    // ---- phase 2: G-apply on 0..nG-1  ||  trailing update on nG..511 (disjoint) ----
    if (tid < nG) {
      int q = tid / NB, j = tid - (tid / NB) * NB;
      int qI = q * NB;
      float w[NB];
      #pragma unroll
      for (int m = 0; m < NB; ++m) w[m] = Tst[q][m][j];
      float rn[NB];
      #pragma unroll
      for (int i = 0; i < NB; ++i) {
        float s = 0.0f;
        #pragma unroll
        for (int m = 0; m <= i; ++m) s += GT[j0 + m][j0 + i] * w[m];  // broadcast
        rn[i] = -s;
      }
      float4* dst = reinterpret_cast<float4*>(&GT[qI + j][j0]);
      float4 r0 = {rn[0], rn[1], rn[2], rn[3]};
      float4 r1 = {rn[4], rn[5], rn[6], rn[7]};
      float4 r2 = {rn[8], rn[9], rn[10], rn[11]};
      dst[0] = r0; dst[1] = r1; dst[2] = r2;
    } else {
      int nt = nbrows / 4;
      int ntasks = nt * (nt + 1) / 2;
      int nthr = 512 - nG;
      for (int t = tid - nG; t < ntasks; t += nthr) {
        int r4 = (int)((sqrtf(8.0f * (float)t + 1.0f) - 1.0f) * 0.5f);
        while ((r4 + 1) * (r4 + 2) / 2 <= t) ++r4;
        while (r4 * (r4 + 1) / 2 > t) --r4;
        int c4 = t - r4 * (r4 + 1) / 2;
        int r = j1 + r4 * 4, c = j1 + c4 * 4;
        float pr[4][NB], pc[4][NB];
        #pragma unroll
        for (int i = 0; i < 4; ++i) {
          float4 a0 = *reinterpret_cast<const float4*>(&A[r + i][j0]);
          float4 a1 = *reinterpret_cast<const float4*>(&A[r + i][j0 + 4]);
          float4 a2 = *reinterpret_cast<const float4*>(&A[r + i][j0 + 8]);
          pr[i][0] = a0.x; pr[i][1] = a0.y; pr[i][2] = a0.z; pr[i][3] = a0.w;
          pr[i][4] = a1.x; pr[i][5] = a1.y; pr[i][6] = a1.z; pr[i][7] = a1.w;
          pr[i][8] = a2.x; pr[i][9] = a2.y; pr[i][10] = a2.z; pr[i][11] = a2.w;
          float4 b0 = *reinterpret_cast<const float4*>(&A[c + i][j0]);
          float4 b1 = *reinterpret_cast<const float4*>(&A[c + i][j0 + 4]);
          float4 b2 = *reinterpret_cast<const float4*>(&A[c + i][j0 + 8]);
          pc[i][0] = b0.x; pc[i][1] = b0.y; pc[i][2] = b0.z; pc[i][3] = b0.w;
          pc[i][4] = b1.x; pc[i][5] = b1.y; pc[i][6] = b1.z; pc[i][7] = b1.w;
          pc[i][8] = b2.x; pc[i][9] = b2.y; pc[i][10] = b2.z; pc[i][11] = b2.w;
        }
        float4 av[4];
        #pragma unroll
        for (int i = 0; i < 4; ++i)
          av[i] = *reinterpret_cast<const float4*>(&A[r + i][c]);
        #pragma unroll
        for (int k = 0; k < NB; ++k) {
          #pragma unroll
          for (int i = 0; i < 4; ++i) {
            av[i].x -= pr[i][k] * pc[0][k];
            av[i].y -= pr[i][k] * pc[1][k];
            av[i].z -= pr[i][k] * pc[2][k];
            av[i].w -= pr[i][k] * pc[3][k];
          }
        }
        #pragma unroll
        for (int i = 0; i < 4; ++i)
          *reinterpret_cast<float4*>(&A[r + i][c]) = av[i];
      }
    }
    __syncthreads();
  }

  // ---- write GT to global ----
  for (int idx = tid; idx < NP * NP; idx += 512) {
    int r = idx / NP, c = idx - r * NP;
    Gg[idx] = GT[r][c];
  }

  // ---- logdet from diag(G) = 1/diag(L) ----
  float lg = (tid < NP) ? logf(GT[tid][tid]) : 0.0f;
  #pragma unroll
  for (int off = 32; off > 0; off >>= 1) lg += __shfl_down(lg, off, 64);
  __syncthreads();
  if ((tid & 63) == 0) redB[tid >> 6] = lg;
  __syncthreads();
  if (tid == 0) {
    float sgl = 0.0f;
    #pragma unroll
    for (int i = 0; i < 8; ++i) sgl += redB[i];
    scalars[2] = -2.0f * sgl;            // logdet(M)
  }
}

__device__ void gemm_body(GemmSh& sh, const float* __restrict__ x,
                          const unsigned short* __restrict__ VbT,
                          unsigned short* __restrict__ Yb,
                          float* __restrict__ tvec, int blk) {
  auto& Xs = sh.Xs;
  auto& Vs = sh.Vs;
  int tid = threadIdx.x;                 // 512 threads
  int row0 = blk * GBM;
  int wid = tid >> 6, lane = tid & 63;
  int lr = lane & 15, lk = (lane >> 4) * 8;
  int rt = wid & 1;
  int cg = wid >> 1;
  int ct0 = (cg == 0) ? 0 : (cg * 2 + 1);
  int nct = (cg == 0) ? 3 : 2;

  int sxr = tid >> 4;
  int sxk = (tid & 15) * 8;
  int vrb = tid >> 4;
  int vk  = (tid & 15) * 8;

  float4 xr0, xr1;
  uint4 vr0, vr1, vr2, vr3, vr4;
  {
    const float* xb = &x[(size_t)(row0 + sxr) * D + sxk];
    xr0 = *reinterpret_cast<const float4*>(xb);
    xr1 = *reinterpret_cast<const float4*>(xb + 4);
    const unsigned short* vb = &VbT[(size_t)vrb * D + vk];
    vr0 = *reinterpret_cast<const uint4*>(vb);
    vr1 = *reinterpret_cast<const uint4*>(vb + (size_t)32 * D);
    vr2 = *reinterpret_cast<const uint4*>(vb + (size_t)64 * D);
    vr3 = *reinterpret_cast<const uint4*>(vb + (size_t)96 * D);
    if (tid < 256) vr4 = *reinterpret_cast<const uint4*>(vb + (size_t)128 * D);
  }

  f32x4 acc0 = {0, 0, 0, 0}, acc1 = {0, 0, 0, 0}, acc2 = {0, 0, 0, 0};

  for (int s = 0; s < NSTEP; ++s) {
    {
      uint4 w;
      w.x = (unsigned)f2bf(xr0.x) | ((unsigned)f2bf(xr0.y) << 16);
      w.y = (unsigned)f2bf(xr0.z) | ((unsigned)f2bf(xr0.w) << 16);
      w.z = (unsigned)f2bf(xr1.x) | ((unsigned)f2bf(xr1.y) << 16);
      w.w = (unsigned)f2bf(xr1.z) | ((unsigned)f2bf(xr1.w) << 16);
      *reinterpret_cast<uint4*>(&Xs[sxr][sxk]) = w;
      unsigned short* vd = &Vs[vrb][vk];
      *reinterpret_cast<uint4*>(vd) = vr0;
      *reinterpret_cast<uint4*>(vd + 32 * XSS) = vr1;
      *reinterpret_cast<uint4*>(vd + 64 * XSS) = vr2;
      *reinterpret_cast<uint4*>(vd + 96 * XSS) = vr3;
      if (tid < 256) *reinterpret_cast<uint4*>(vd + 128 * XSS) = vr4;
    }
    __syncthreads();
    if (s + 1 < NSTEP) {
      const float* xb = &x[(size_t)(row0 + sxr) * D + (s + 1) * GBK + sxk];
      xr0 = *reinterpret_cast<const float4*>(xb);
      xr1 = *reinterpret_cast<const float4*>(xb + 4);
      const unsigned short* vb = &VbT[(size_t)vrb * D + (s + 1) * GBK + vk];
      vr0 = *reinterpret_cast<const uint4*>(vb);
      vr1 = *reinterpret_cast<const uint4*>(vb + (size_t)32 * D);
      vr2 = *reinterpret_cast<const uint4*>(vb + (size_t)64 * D);
      vr3 = *reinterpret_cast<const uint4*>(vb + (size_t)96 * D);
      if (tid < 256) vr4 = *reinterpret_cast<const uint4*>(vb + (size_t)128 * D);
    }
    #pragma unroll
    for (int ks = 0; ks < 4; ++ks) {
      bh8 a = *reinterpret_cast<const bh8*>(&Xs[rt * 16 + lr][ks * 32 + lk]);
      bh8 b0 = *reinterpret_cast<const bh8*>(&Vs[ct0 * 16 + lr][ks * 32 + lk]);
      acc0 = __builtin_amdgcn_mfma_f32_16x16x32_bf16(a, b0, acc0, 0, 0, 0);
      bh8 b1 = *reinterpret_cast<const bh8*>(&Vs[(ct0 + 1) * 16 + lr][ks * 32 + lk]);
      acc1 = __builtin_amdgcn_mfma_f32_16x16x32_bf16(a, b1, acc1, 0, 0, 0);
      if (nct == 3) {
        bh8 b2 = *reinterpret_cast<const bh8*>(&Vs[(ct0 + 2) * 16 + lr][ks * 32 + lk]);
        acc2 = __builtin_amdgcn_mfma_f32_16x16x32_bf16(a, b2, acc2, 0, 0, 0);
      }
    }
    __syncthreads();
  }

  // ---- epilogue: write bf16 Yb (C/D layout col=lane&15, row=(lane>>4)*4+g) ----
  int rw = row0 + rt * 16 + ((lane >> 4) << 2);
  #pragma unroll
  for (int g = 0; g < 4; ++g)
    Yb[(size_t)(rw + g) * NC + ct0 * 16 + lr] = f2bf(acc0[g]);
  #pragma unroll
  for (int g = 0; g < 4; ++g)
    Yb[(size_t)(rw + g) * NC + (ct0 + 1) * 16 + lr] = f2bf(acc1[g]);
  if (nct == 3) {
    #pragma unroll
    for (int g = 0; g < 4; ++g)
      Yb[(size_t)(rw + g) * NC + (ct0 + 2) * 16 + lr] = f2bf(acc2[g]);
  }

  // ---- tvec partials from fp32 acc: column sums via shfl_xor over row groups ----
  {
    float c0 = acc0[0] + acc0[1] + acc0[2] + acc0[3];
    c0 += __shfl_xor(c0, 16, 64);
    c0 += __shfl_xor(c0, 32, 64);
    float c1 = acc1[0] + acc1[1] + acc1[2] + acc1[3];
    c1 += __shfl_xor(c1, 16, 64);
    c1 += __shfl_xor(c1, 32, 64);
    float c2 = 0.0f;
    if (nct == 3) {
      c2 = acc2[0] + acc2[1] + acc2[2] + acc2[3];
      c2 += __shfl_xor(c2, 16, 64);
      c2 += __shfl_xor(c2, 32, 64);
    }
    if ((lane >> 4) == 0) {              // lanes 0..15 hold full 16-row sums
      atomicAdd(&tvec[ct0 * 16 + lr], c0);
      atomicAdd(&tvec[(ct0 + 1) * 16 + lr], c1);
      if (nct == 3) atomicAdd(&tvec[(ct0 + 2) * 16 + lr], c2);
    }
  }
}

// colstats: term1 = sum (x-mu)^2/sigma; block 0 also sum(log sigma)
__device__ void colstats_body(const float* __restrict__ x,
                              const float* __restrict__ theta,
                              float* __restrict__ scalars, int cb) {
  int i0 = cb * CS_ROWS;
  const float* mu = theta + (size_t)D * K;
  const float* sg = mu + D;
  int dA = threadIdx.x * 4, dB = (threadIdx.x + 512) * 4;
  float4 muA = *reinterpret_cast<const float4*>(&mu[dA]);
  float4 sgA = *reinterpret_cast<const float4*>(&sg[dA]);
  float4 muB = *reinterpret_cast<const float4*>(&mu[dB]);
  float4 sgB = *reinterpret_cast<const float4*>(&sg[dB]);
  float4 ivA = {1.0f / sgA.x, 1.0f / sgA.y, 1.0f / sgA.z, 1.0f / sgA.w};
  float4 ivB = {1.0f / sgB.x, 1.0f / sgB.y, 1.0f / sgB.z, 1.0f / sgB.w};
  float t1 = 0.0f;
  for (int i = i0; i < i0 + CS_ROWS; ++i) {
    float4 a = *reinterpret_cast<const float4*>(&x[(size_t)i * D + dA]);
    float4 b = *reinterpret_cast<const float4*>(&x[(size_t)i * D + dB]);
    float ax = a.x - muA.x, ay = a.y - muA.y, az = a.z - muA.z, aw = a.w - muA.w;
    float bx = b.x - muB.x, by = b.y - muB.y, bz = b.z - muB.z, bw = b.w - muB.w;
    t1 += ax * ax * ivA.x + ay * ay * ivA.y + az * az * ivA.z + aw * aw * ivA.w;
    t1 += bx * bx * ivB.x + by * by * ivB.y + bz * bz * ivB.z + bw * bw * ivB.w;
  }
  float r = blockReduceSum512(t1);
  if (threadIdx.x == 0) atomicAdd(&scalars[1], r);
  if (cb == 0) {
    float lg = logf(sgA.x) + logf(sgA.y) + logf(sgA.z) + logf(sgA.w)
             + logf(sgB.x) + logf(sgB.y) + logf(sgB.z) + logf(sgB.w);
    float r2 = blockReduceSum512(lg);
    if (threadIdx.x == 0) atomicAdd(&scalars[0], r2);
  }
}

__global__ __launch_bounds__(512, 1) void k_par(const float* __restrict__ x,
                                                const float* __restrict__ theta,
                                                const unsigned short* __restrict__ VbT,
                                                unsigned short* __restrict__ Yb,
                                                const float* __restrict__ Mg,
                                                float* __restrict__ Gg,
                                                float* __restrict__ scalars,
                                                float* __restrict__ tvec) {
  __shared__ ParSh sh;
  int b = blockIdx.x;
  if (b == 0) {
    chol_body(sh.c, Mg, Gg, scalars);
  } else if (b <= GEMM_BLOCKS) {
    gemm_body(sh.g, x, VbT, Yb, tvec, b - 1);
  } else {
    colstats_body(x, theta, scalars, b - 1 - GEMM_BLOCKS);
  }
}

// ---------------- Q += Yb^T Yb  (bf16 in, symmetry, row-split atomics) ----------------
#define SYRK_ZSPLIT 16
__global__ __launch_bounds__(256) void k_syrk(const unsigned short* __restrict__ Yb,
                                              float* __restrict__ Q) {
  int bj = blockIdx.x * 16, bk = blockIdx.y * 16;
  if (bk < bj) return;                   // symmetry (upper only; trace reads upper)
  __shared__ float Ya[64][17];
  __shared__ float Yc[64][17];
  int i0base = blockIdx.z * (NROWS / SYRK_ZSPLIT);
  int tid = threadIdx.x;
  int tj = tid & 15, tk = tid >> 4;
  int lr = tid >> 2, lc = (tid & 3) * 4;
  float acc = 0.0f;
  for (int i0 = i0base; i0 < i0base + NROWS / SYRK_ZSPLIT; i0 += 64) {
    ushort4 va = *reinterpret_cast<const ushort4*>(&Yb[(size_t)(i0 + lr) * NC + bj + lc]);
    ushort4 vc = *reinterpret_cast<const ushort4*>(&Yb[(size_t)(i0 + lr) * NC + bk + lc]);
    Ya[lr][lc + 0] = bf2f(va.x); Ya[lr][lc + 1] = bf2f(va.y);
    Ya[lr][lc + 2] = bf2f(va.z); Ya[lr][lc + 3] = bf2f(va.w);
    Yc[lr][lc + 0] = bf2f(vc.x); Yc[lr][lc + 1] = bf2f(vc.y);
    Yc[lr][lc + 2] = bf2f(vc.z); Yc[lr][lc + 3] = bf2f(vc.w);
    __syncthreads();
    #pragma unroll
    for (int ii = 0; ii < 64; ++ii) acc += Ya[ii][tj] * Yc[ii][tk];
    __syncthreads();
  }
  atomicAdd(&Q[(bj + tj) * QS + bk + tk], acc);
}

// ---------------- k_trace: tr(M^-1 S) via GT row-dots + final combine ----------------
__global__ __launch_bounds__(256) void k_trace(const float* __restrict__ Gg,
                                               const float* __restrict__ Qg,
                                               const float* __restrict__ tvec,
                                               const float* __restrict__ mvec,
                                               float* __restrict__ scalars,
                                               const int* __restrict__ fds,
                                               float* __restrict__ out) {
  int b = blockIdx.x;                    // 0..44 -> upper tile pair (tjT <= tkT)
  int tkT = (int)((sqrtf(8.0f * (float)b + 1.0f) - 1.0f) * 0.5f);
  while ((tkT + 1) * (tkT + 2) / 2 <= b) ++tkT;
  while (tkT * (tkT + 1) / 2 > b) --tkT;
  int tjT = b - tkT * (tkT + 1) / 2;
  int bj = tjT * 16, bk = tkT * 16;
  int tj = threadIdx.x & 15, tk = threadIdx.x >> 4;
  int j = bj + tj, k = bk + tk;
  float acc = 0.0f;
  if (j <= k && k < NP && j < KP && k < KP) {
    const float* gj = Gg + (size_t)j * NP;
    const float* gk = Gg + (size_t)k * NP;
    float h0 = 0.f, h1 = 0.f;
    #pragma unroll 4
    for (int i4 = 0; i4 < NP / 4; ++i4) {
      float4 a = *reinterpret_cast<const float4*>(gj + i4 * 4);
      float4 c = *reinterpret_cast<const float4*>(gk + i4 * 4);
      h0 += a.x * c.x + a.y * c.y;
      h1 += a.z * c.z + a.w * c.w;
    }
    float h = h0 + h1;
    float tlj = tvec[j], mlj = mvec[j], tlk = tvec[k], mlk = mvec[k];
    float S = Qg[j * QS + k] - tlj * mlk - mlj * tlk + (float)NROWS * mlj * mlk;
    acc = ((j == k) ? 1.0f : 2.0f) * h * S;
  }
  float r = blockReduceSum256(acc);
  if (threadIdx.x == 0) {
    atomicAdd(&scalars[3], r);
    __threadfence();
    unsigned old = atomicAdd(reinterpret_cast<unsigned int*>(scalars + 4), 1u);
    if (old == NTRACE - 1) {             // last block combines
      float tr = atomicAdd(&scalars[3], 0.0f);   // device-coherent read
      double sumlog  = (double)scalars[0];
      double term1   = (double)scalars[1];
      double logdetM = (double)scalars[2];
      double total = (double)NROWS * (double)D * LOG2PI
                   + (double)NROWS * (sumlog + logdetM)
                   + term1 - (double)tr;
      double scale = (double)fds[0] / (double)NROWS;
      out[0] = (float)(scale * (-0.5) * total);
    }
  }
}

// ---------------- launch ----------------
extern "C" void kernel_launch(void* const* d_in, const int* in_sizes, int n_in,
                              void* d_out, int out_size, void* d_ws, size_t ws_size,
                              hipStream_t stream) {
  const float* x     = (const float*)d_in[0];
  const float* theta = (const float*)d_in[1];
  const int*   fds   = (const int*)d_in[2];
  float* out = (float*)d_out;
  float* ws = (float*)d_ws;

  // zeroed region first: Q | tvec | scalars | mvec (contiguous; mvec is atomic now)
  float* Q        = ws;                          // QS*QS = 20736
  float* tvec     = Q + QS * QS;                 // NC (atomic col sums)
  float* scalars  = tvec + NC;                   // 8
  float* mvec     = scalars + 8;                 // NC (atomic, from k_prep)
  unsigned short* Yb  = (unsigned short*)(mvec + NC);      // NROWS*NC bf16
  unsigned short* VbT = Yb + (size_t)NROWS * NC;           // NC*D bf16
  float* M        = (float*)(VbT + (size_t)NC * D);        // KP*MS
  float* Gg       = M + KP * MS;                 // NP*NP (stores G^T)

  hipMemsetAsync(Q, 0, (size_t)(QS * QS + NC + 8 + NC) * sizeof(float), stream);

  k_prep <<<dim3(D / PD), 256, 0, stream>>>(theta, VbT, mvec);
  k_M    <<<dim3(KP, KP), 256, 0, stream>>>(theta, VbT, M);
  k_par  <<<dim3(1 + GEMM_BLOCKS + CS_BLOCKS), 512, 0, stream>>>(
             x, theta, VbT, Yb, M, Gg, scalars, tvec);
  k_syrk <<<dim3(QS / 16, QS / 16, SYRK_ZSPLIT), 256, 0, stream>>>(Yb, Q);
  k_trace<<<dim3(NTRACE), 256, 0, stream>>>(Gg, Q, tvec, mvec, scalars, fds, out);
}

// Round 19
// 143.090 us; speedup vs baseline: 1.4165x; 1.4165x over previous
//
#include <hip/hip_runtime.h>
#include <math.h>

#define D 4096
#define K 128
#define KP 129          // K+1 (augmented sqrt(EPS)*ones column)
#define NC 144          // padded col count for VbT / Yb (9 tiles of 16; cols >= 129 zero)
#define NROWS 8192
#define QS 144          // Q row stride
#define MS 132          // M row stride
#define NP 132          // padded order for chol
#define NPS 136         // LDS row stride (float4-aligned)
#define NB 12           // panel width (11 panels)
#define NPAN (NP / NB)
#define MSPLIT 3        // T2 accumulation row-split (4 rows/thread); 128+3*120=488<=512
#define NTRACE 45       // 9*10/2 trace tile-pairs
#define LOG2PI 1.8378770664093453

typedef __attribute__((ext_vector_type(8))) short bh8;     // 8 bf16 (4 VGPRs)
typedef __attribute__((ext_vector_type(4))) float f32x4;   // MFMA acc

// ---------------- helpers ----------------
__device__ __forceinline__ unsigned short f2bf(float f) {  // RNE
  unsigned int u = __float_as_uint(f);
  unsigned int r = u + 0x7FFFu + ((u >> 16) & 1u);
  return (unsigned short)(r >> 16);
}
__device__ __forceinline__ float bf2f(unsigned short u) {
  return __uint_as_float(((unsigned int)u) << 16);
}
__device__ __forceinline__ float blo(unsigned int v) { return __uint_as_float(v << 16); }
__device__ __forceinline__ float bhi(unsigned int v) { return __uint_as_float(v & 0xFFFF0000u); }

__device__ __forceinline__ float blockReduceSum256(float v) {
  #pragma unroll
  for (int off = 32; off > 0; off >>= 1) v += __shfl_down(v, off, 64);
  __shared__ float tmp[4];
  __syncthreads();
  if ((threadIdx.x & 63) == 0) tmp[threadIdx.x >> 6] = v;
  __syncthreads();
  float r = 0.0f;
  if (threadIdx.x == 0) r = tmp[0] + tmp[1] + tmp[2] + tmp[3];
  return r;                              // valid on tid 0 only
}

__device__ __forceinline__ float blockReduceSum512(float v) {
  #pragma unroll
  for (int off = 32; off > 0; off >>= 1) v += __shfl_down(v, off, 64);
  __shared__ float tmp8[8];
  __syncthreads();
  if ((threadIdx.x & 63) == 0) tmp8[threadIdx.x >> 6] = v;
  __syncthreads();
  float r = 0.0f;
  if (threadIdx.x == 0) {
    #pragma unroll
    for (int i = 0; i < 8; ++i) r += tmp8[i];
  }
  return r;                              // valid on tid 0 only
}

// ---------------- k_prep: coalesced LDS-transpose (no fused mvec) ----------------
// VbT[c][d] = bf16( U[d][c] / sigma[d] ), rows c>=129 zero
#define PD 64                            // d-rows per block
__global__ __launch_bounds__(256) void k_prep(const float* __restrict__ theta,
                                              unsigned short* __restrict__ VbT) {
  __shared__ float Wt[PD][K + 4];        // W tile (row-major slice)
  __shared__ float isg[PD], alp[K];
  int tid = threadIdx.x;
  int d0 = blockIdx.x * PD;
  const float* sg = theta + (size_t)D * K + D;
  const float* al = sg + D;

  // coalesced load of W rows d0..d0+63 (64*128 floats = 2048 float4)
  #pragma unroll
  for (int it = 0; it < 8; ++it) {
    int f4 = tid + it * 256;             // 0..2047
    int base = f4 * 4;
    int r = base >> 7, c = base & 127;
    float4 w = *reinterpret_cast<const float4*>(&theta[(size_t)(d0 + r) * K + c]);
    *reinterpret_cast<float4*>(&Wt[r][c]) = w;
  }
  if (tid < PD)            isg[tid] = 1.0f / sg[d0 + tid];
  else if (tid >= 128)     alp[tid - 128] = al[tid - 128];
  __syncthreads();

  // 9 passes of 16 columns; 16 threads per column, 4 d-values per thread
  int cl = tid >> 4;                     // 0..15 within pass
  int dl = (tid & 15) * 4;
  for (int pc = 0; pc < 9; ++pc) {
    int c = pc * 16 + cl;
    float v0, v1, v2, v3;
    if (c < K) {
      float a = alp[c];
      v0 = Wt[dl + 0][c] * a * isg[dl + 0];
      v1 = Wt[dl + 1][c] * a * isg[dl + 1];
      v2 = Wt[dl + 2][c] * a * isg[dl + 2];
      v3 = Wt[dl + 3][c] * a * isg[dl + 3];
    } else if (c == K) {
      v0 = 1.0e-3f * isg[dl + 0];
      v1 = 1.0e-3f * isg[dl + 1];
      v2 = 1.0e-3f * isg[dl + 2];
      v3 = 1.0e-3f * isg[dl + 3];
    } else {
      v0 = v1 = v2 = v3 = 0.0f;
    }
    ushort4 w;
    w.x = f2bf(v0); w.y = f2bf(v1); w.z = f2bf(v2); w.w = f2bf(v3);
    *reinterpret_cast<ushort4*>(&VbT[(size_t)c * D + d0 + dl]) = w;
  }
}

// ---------------- M = I + sum_d sigma_d VbT[j][d] VbT[k][d] ----------------
__global__ __launch_bounds__(256) void k_M(const float* __restrict__ theta,
                                           const unsigned short* __restrict__ VbT,
                                           float* __restrict__ M) {
  int j = blockIdx.x, kk2 = blockIdx.y;
  if (kk2 < j) return;                   // symmetry
  const float* sg = theta + (size_t)D * K + D;
  float acc = 0.0f;
  for (int d0 = threadIdx.x * 8; d0 < D; d0 += 2048) {
    uint4 ua = *reinterpret_cast<const uint4*>(&VbT[(size_t)j * D + d0]);
    uint4 ub = *reinterpret_cast<const uint4*>(&VbT[(size_t)kk2 * D + d0]);
    float4 s0 = *reinterpret_cast<const float4*>(&sg[d0]);
    float4 s1 = *reinterpret_cast<const float4*>(&sg[d0 + 4]);
    acc += s0.x * blo(ua.x) * blo(ub.x) + s0.y * bhi(ua.x) * bhi(ub.x)
         + s0.z * blo(ua.y) * blo(ub.y) + s0.w * bhi(ua.y) * bhi(ub.y)
         + s1.x * blo(ua.z) * blo(ub.z) + s1.y * bhi(ua.z) * bhi(ub.z)
         + s1.z * blo(ua.w) * blo(ub.w) + s1.w * bhi(ua.w) * bhi(ub.w);
  }
  float r = blockReduceSum256(acc);
  if (threadIdx.x == 0) {
    float m = r + (j == kk2 ? 1.0f : 0.0f);
    M[j * MS + kk2] = m;
    M[kk2 * MS + j] = m;
  }
}

// ================= fused parallel kernel (512 threads/block) =================
// block 0: chol | 1..256: gemm(+tvec) | 257..288: colstats(term1,sumlog) | 289..417: mvec
#define GBM 32
#define GBK 128
#define NSTEP (D / GBK)     // 32
#define XSS 136             // LDS row stride in shorts
#define GEMM_BLOCKS (NROWS / GBM)   // 256
#define CS_BLOCKS 32
#define CS_ROWS (NROWS / CS_BLOCKS) // 256

struct CholSh {
  float A[NP][NPS];
  float GT[NP][NPS];       // GT[col][row] = G[row][col] = L^-1 transposed
  float Tst[NPAN][NB][NB + 1];
};
struct GemmSh {
  unsigned short Xs[GBM][XSS];
  unsigned short Vs[NC][XSS];
};
union ParSh {
  CholSh c;
  GemmSh g;
};

__device__ void chol_body(CholSh& sh, const float* __restrict__ Mg,
                          float* __restrict__ Gg, float* __restrict__ scalars) {
  auto& A = sh.A;
  auto& GT = sh.GT;
  auto& Tst = sh.Tst;
  __shared__ float redB[8];
  int tid = threadIdx.x;

  for (int idx = tid; idx < NP * NP; idx += 512) {
    int r = idx / NP, c = idx - r * NP;
    A[r][c] = (r < KP && c < KP) ? Mg[r * MS + c] : (r == c ? 1.0f : 0.0f);
  }
  // zero GT fully (upper blocks are read by full-range dots in k_trace)
  {
    float* gt = &GT[0][0];
    for (int idx = tid; idx < NP * NPS; idx += 512) gt[idx] = 0.0f;
  }
  __syncthreads();

  // ---- blocked Cholesky with fused triangular inverse; G stored TRANSPOSED ----
  for (int p = 0; p < NPAN; ++p) {
    int j0 = p * NB, j1 = j0 + NB;
    int nbrows = NP - j1;
    int nG = p * NB;                     // threads doing G-apply in phase 2
    if (tid < 128) {
      float T[NB][NB];
      #pragma unroll
      for (int r = 0; r < NB; ++r)
        #pragma unroll
        for (int c = 0; c <= r; ++c)
          T[r][c] = A[j0 + r][j0 + c];
      float dinv[NB];
      #pragma unroll
      for (int jj = 0; jj < NB; ++jj) {
        float dv = sqrtf(T[jj][jj]);
        float iv = 1.0f / dv;
        dinv[jj] = iv;
        #pragma unroll
        for (int r = jj + 1; r < NB; ++r) T[r][jj] *= iv;
        #pragma unroll
        for (int cc = jj + 1; cc < NB; ++cc)
          #pragma unroll
          for (int r = cc; r < NB; ++r)
            T[r][cc] -= T[r][jj] * T[cc][jj];
      }
      #pragma unroll
      for (int r = 0; r < NB; ++r) {     // in-place row-wise inverse -> G_pp
        float tmp[NB];
        #pragma unroll
        for (int c = 0; c < r; ++c) {
          float s = 0.0f;
          #pragma unroll
          for (int k = c; k < r; ++k) s += T[r][k] * T[k][c];
          tmp[c] = -s * dinv[r];
        }
        #pragma unroll
        for (int c = 0; c < r; ++c) T[r][c] = tmp[c];
        T[r][r] = dinv[r];
      }
      if (tid == 0) {                    // stash G_pp TRANSPOSED: GT[j0+c][j0+r] = T[r][c]
        #pragma unroll
        for (int c = 0; c < NB; ++c) {
          float g[NB];
          #pragma unroll
          for (int r = 0; r < NB; ++r) g[r] = (r >= c) ? T[r][c] : 0.0f;
          float4* dst = reinterpret_cast<float4*>(&GT[j0 + c][j0]);
          float4 g0 = {g[0], g[1], g[2], g[3]};
          float4 g1 = {g[4], g[5], g[6], g[7]};
          float4 g2 = {g[8], g[9], g[10], g[11]};
          dst[0] = g0; dst[1] = g1; dst[2] = g2;
        }
      }
      if (tid < nbrows) {                // fused panel solve, G_pp from registers
        int r = j1 + tid;
        float* arow = &A[r][j0];
        float4 q0 = *reinterpret_cast<const float4*>(arow);
        float4 q1 = *reinterpret_cast<const float4*>(arow + 4);
        float4 q2 = *reinterpret_cast<const float4*>(arow + 8);
        float ro[NB] = {q0.x, q0.y, q0.z, q0.w, q1.x, q1.y, q1.z, q1.w,
                        q2.x, q2.y, q2.z, q2.w};
        float rn[NB];
        #pragma unroll
        for (int cc = 0; cc < NB; ++cc) {
          float s = 0.0f;
          #pragma unroll
          for (int k = 0; k <= cc; ++k) s += ro[k] * T[cc][k];
          rn[cc] = s;
        }
        float4 w0 = {rn[0], rn[1], rn[2], rn[3]};
        float4 w1 = {rn[4], rn[5], rn[6], rn[7]};
        float4 w2 = {rn[8], rn[9], rn[10], rn[11]};
        *reinterpret_cast<float4*>(arow) = w0;
        *reinterpret_cast<float4*>(arow + 4) = w1;
        *reinterpret_cast<float4*>(arow + 8) = w2;
      }
    } else if (tid < 128 + MSPLIT * nG) {
      // T2[m] = sum_{k=q..p-1} <A[j0+m][kI..], GT[qI+j][kI..]> (float4 dots)
      int t2 = tid - 128;
      int q = t2 / (NB * MSPLIT);
      int rem = t2 - q * (NB * MSPLIT);
      int j = rem % NB, mg = rem / NB;   // mg in 0..2
      int qI = q * NB;
      int m0 = mg * 4;
      float t0 = 0.0f, t1 = 0.0f, t2a = 0.0f, t3 = 0.0f;
      for (int k = q; k < p; ++k) {
        int kI = k * NB;
        const float* gp = &GT[qI + j][kI];
        float4 g0 = *reinterpret_cast<const float4*>(gp);
        float4 g1 = *reinterpret_cast<const float4*>(gp + 4);
        float4 g2 = *reinterpret_cast<const float4*>(gp + 8);
        #pragma unroll
        for (int i = 0; i < 4; ++i) {
          const float* ap = &A[j0 + m0 + i][kI];
          float4 a0 = *reinterpret_cast<const float4*>(ap);
          float4 a1 = *reinterpret_cast<const float4*>(ap + 4);
          float4 a2 = *reinterpret_cast<const float4*>(ap + 8);
          float s = a0.x * g0.x + a0.y * g0.y + a0.z * g0.z + a0.w * g0.w
                  + a1.x * g1.x + a1.y * g1.y + a1.z * g1.z + a1.w * g1.w
                  + a2.x * g2.x + a2.y * g2.y + a2.z * g2.z + a2.w * g2.w;
          if (i == 0) t0 += s;
          else if (i == 1) t1 += s;
          else if (i == 2) t2a += s;
          else t3 += s;
        }
      }
      Tst[q][m0 + 0][j] = t0;
      Tst[q][m0 + 1][j] = t1;
      Tst[q][m0 + 2][j] = t2a;
      Tst[q][m0 + 3][j] = t3;
    }
    __syncthreads();
    // ---- phase 2: G-apply on 0..nG-1  ||  trailing update on nG..511 (disjoint) ----
    if (tid < nG) {
      int q = tid / NB, j = tid - (tid / NB) * NB;
      int qI = q * NB;
      float w[NB];
      #pragma unroll
      for (int m = 0; m < NB; ++m) w[m] = Tst[q][m][j];
      float rn[NB];
      #pragma unroll
      for (int i = 0; i < NB; ++i) {
        float s = 0.0f;
        #pragma unroll
        for (int m = 0; m <= i; ++m) s += GT[j0 + m][j0 + i] * w[m];  // broadcast
        rn[i] = -s;
      }
      float4* dst = reinterpret_cast<float4*>(&GT[qI + j][j0]);
      float4 r0 = {rn[0], rn[1], rn[2], rn[3]};
      float4 r1 = {rn[4], rn[5], rn[6], rn[7]};
      float4 r2 = {rn[8], rn[9], rn[10], rn[11]};
      dst[0] = r0; dst[1] = r1; dst[2] = r2;
    } else {
      int nt = nbrows / 4;
      int ntasks = nt * (nt + 1) / 2;
      int nthr = 512 - nG;
      for (int t = tid - nG; t < ntasks; t += nthr) {
        int r4 = (int)((sqrtf(8.0f * (float)t + 1.0f) - 1.0f) * 0.5f);
        while ((r4 + 1) * (r4 + 2) / 2 <= t) ++r4;
        while (r4 * (r4 + 1) / 2 > t) --r4;
        int c4 = t - r4 * (r4 + 1) / 2;
        int r = j1 + r4 * 4, c = j1 + c4 * 4;
        float pr[4][NB], pc[4][NB];
        #pragma unroll
        for (int i = 0; i < 4; ++i) {
          float4 a0 = *reinterpret_cast<const float4*>(&A[r + i][j0]);
          float4 a1 = *reinterpret_cast<const float4*>(&A[r + i][j0 + 4]);
          float4 a2 = *reinterpret_cast<const float4*>(&A[r + i][j0 + 8]);
          pr[i][0] = a0.x; pr[i][1] = a0.y; pr[i][2] = a0.z; pr[i][3] = a0.w;
          pr[i][4] = a1.x; pr[i][5] = a1.y; pr[i][6] = a1.z; pr[i][7] = a1.w;
          pr[i][8] = a2.x; pr[i][9] = a2.y; pr[i][10] = a2.z; pr[i][11] = a2.w;
          float4 b0 = *reinterpret_cast<const float4*>(&A[c + i][j0]);
          float4 b1 = *reinterpret_cast<const float4*>(&A[c + i][j0 + 4]);
          float4 b2 = *reinterpret_cast<const float4*>(&A[c + i][j0 + 8]);
          pc[i][0] = b0.x; pc[i][1] = b0.y; pc[i][2] = b0.z; pc[i][3] = b0.w;
          pc[i][4] = b1.x; pc[i][5] = b1.y; pc[i][6] = b1.z; pc[i][7] = b1.w;
          pc[i][8] = b2.x; pc[i][9] = b2.y; pc[i][10] = b2.z; pc[i][11] = b2.w;
        }
        float4 av[4];
        #pragma unroll
        for (int i = 0; i < 4; ++i)
          av[i] = *reinterpret_cast<const float4*>(&A[r + i][c]);
        #pragma unroll
        for (int k = 0; k < NB; ++k) {
          #pragma unroll
          for (int i = 0; i < 4; ++i) {
            av[i].x -= pr[i][k] * pc[0][k];
            av[i].y -= pr[i][k] * pc[1][k];
            av[i].z -= pr[i][k] * pc[2][k];
            av[i].w -= pr[i][k] * pc[3][k];
          }
        }
        #pragma unroll
        for (int i = 0; i < 4; ++i)
          *reinterpret_cast<float4*>(&A[r + i][c]) = av[i];
      }
    }
    __syncthreads();
  }

  // ---- write GT to global ----
  for (int idx = tid; idx < NP * NP; idx += 512) {
    int r = idx / NP, c = idx - r * NP;
    Gg[idx] = GT[r][c];
  }

  // ---- logdet from diag(G) = 1/diag(L) ----
  float lg = (tid < NP) ? logf(GT[tid][tid]) : 0.0f;
  #pragma unroll
  for (int off = 32; off > 0; off >>= 1) lg += __shfl_down(lg, off, 64);
  __syncthreads();
  if ((tid & 63) == 0) redB[tid >> 6] = lg;
  __syncthreads();
  if (tid == 0) {
    float sgl = 0.0f;
    #pragma unroll
    for (int i = 0; i < 8; ++i) sgl += redB[i];
    scalars[2] = -2.0f * sgl;            // logdet(M)
  }
}

__device__ void gemm_body(GemmSh& sh, const float* __restrict__ x,
                          const unsigned short* __restrict__ VbT,
                          unsigned short* __restrict__ Yb,
                          float* __restrict__ tvec, int blk) {
  auto& Xs = sh.Xs;
  auto& Vs = sh.Vs;
  int tid = threadIdx.x;                 // 512 threads
  int row0 = blk * GBM;
  int wid = tid >> 6, lane = tid & 63;
  int lr = lane & 15, lk = (lane >> 4) * 8;
  int rt = wid & 1;
  int cg = wid >> 1;
  int ct0 = (cg == 0) ? 0 : (cg * 2 + 1);
  int nct = (cg == 0) ? 3 : 2;

  int sxr = tid >> 4;
  int sxk = (tid & 15) * 8;
  int vrb = tid >> 4;
  int vk  = (tid & 15) * 8;

  float4 xr0, xr1;
  uint4 vr0, vr1, vr2, vr3, vr4;
  {
    const float* xb = &x[(size_t)(row0 + sxr) * D + sxk];
    xr0 = *reinterpret_cast<const float4*>(xb);
    xr1 = *reinterpret_cast<const float4*>(xb + 4);
    const unsigned short* vb = &VbT[(size_t)vrb * D + vk];
    vr0 = *reinterpret_cast<const uint4*>(vb);
    vr1 = *reinterpret_cast<const uint4*>(vb + (size_t)32 * D);
    vr2 = *reinterpret_cast<const uint4*>(vb + (size_t)64 * D);
    vr3 = *reinterpret_cast<const uint4*>(vb + (size_t)96 * D);
    if (tid < 256) vr4 = *reinterpret_cast<const uint4*>(vb + (size_t)128 * D);
  }

  f32x4 acc0 = {0, 0, 0, 0}, acc1 = {0, 0, 0, 0}, acc2 = {0, 0, 0, 0};

  for (int s = 0; s < NSTEP; ++s) {
    {
      uint4 w;
      w.x = (unsigned)f2bf(xr0.x) | ((unsigned)f2bf(xr0.y) << 16);
      w.y = (unsigned)f2bf(xr0.z) | ((unsigned)f2bf(xr0.w) << 16);
      w.z = (unsigned)f2bf(xr1.x) | ((unsigned)f2bf(xr1.y) << 16);
      w.w = (unsigned)f2bf(xr1.z) | ((unsigned)f2bf(xr1.w) << 16);
      *reinterpret_cast<uint4*>(&Xs[sxr][sxk]) = w;
      unsigned short* vd = &Vs[vrb][vk];
      *reinterpret_cast<uint4*>(vd) = vr0;
      *reinterpret_cast<uint4*>(vd + 32 * XSS) = vr1;
      *reinterpret_cast<uint4*>(vd + 64 * XSS) = vr2;
      *reinterpret_cast<uint4*>(vd + 96 * XSS) = vr3;
      if (tid < 256) *reinterpret_cast<uint4*>(vd + 128 * XSS) = vr4;
    }
    __syncthreads();
    if (s + 1 < NSTEP) {
      const float* xb = &x[(size_t)(row0 + sxr) * D + (s + 1) * GBK + sxk];
      xr0 = *reinterpret_cast<const float4*>(xb);
      xr1 = *reinterpret_cast<const float4*>(xb + 4);
      const unsigned short* vb = &VbT[(size_t)vrb * D + (s + 1) * GBK + vk];
      vr0 = *reinterpret_cast<const uint4*>(vb);
      vr1 = *reinterpret_cast<const uint4*>(vb + (size_t)32 * D);
      vr2 = *reinterpret_cast<const uint4*>(vb + (size_t)64 * D);
      vr3 = *reinterpret_cast<const uint4*>(vb + (size_t)96 * D);
      if (tid < 256) vr4 = *reinterpret_cast<const uint4*>(vb + (size_t)128 * D);
    }
    #pragma unroll
    for (int ks = 0; ks < 4; ++ks) {
      bh8 a = *reinterpret_cast<const bh8*>(&Xs[rt * 16 + lr][ks * 32 + lk]);
      bh8 b0 = *reinterpret_cast<const bh8*>(&Vs[ct0 * 16 + lr][ks * 32 + lk]);
      acc0 = __builtin_amdgcn_mfma_f32_16x16x32_bf16(a, b0, acc0, 0, 0, 0);
      bh8 b1 = *reinterpret_cast<const bh8*>(&Vs[(ct0 + 1) * 16 + lr][ks * 32 + lk]);
      acc1 = __builtin_amdgcn_mfma_f32_16x16x32_bf16(a, b1, acc1, 0, 0, 0);
      if (nct == 3) {
        bh8 b2 = *reinterpret_cast<const bh8*>(&Vs[(ct0 + 2) * 16 + lr][ks * 32 + lk]);
        acc2 = __builtin_amdgcn_mfma_f32_16x16x32_bf16(a, b2, acc2, 0, 0, 0);
      }
    }
    __syncthreads();
  }

  // ---- epilogue: write bf16 Yb (C/D layout col=lane&15, row=(lane>>4)*4+g) ----
  int rw = row0 + rt * 16 + ((lane >> 4) << 2);
  #pragma unroll
  for (int g = 0; g < 4; ++g)
    Yb[(size_t)(rw + g) * NC + ct0 * 16 + lr] = f2bf(acc0[g]);
  #pragma unroll
  for (int g = 0; g < 4; ++g)
    Yb[(size_t)(rw + g) * NC + (ct0 + 1) * 16 + lr] = f2bf(acc1[g]);
  if (nct == 3) {
    #pragma unroll
    for (int g = 0; g < 4; ++g)
      Yb[(size_t)(rw + g) * NC + (ct0 + 2) * 16 + lr] = f2bf(acc2[g]);
  }

  // ---- tvec partials from fp32 acc: column sums via shfl_xor over row groups ----
  {
    float c0 = acc0[0] + acc0[1] + acc0[2] + acc0[3];
    c0 += __shfl_xor(c0, 16, 64);
    c0 += __shfl_xor(c0, 32, 64);
    float c1 = acc1[0] + acc1[1] + acc1[2] + acc1[3];
    c1 += __shfl_xor(c1, 16, 64);
    c1 += __shfl_xor(c1, 32, 64);
    float c2 = 0.0f;
    if (nct == 3) {
      c2 = acc2[0] + acc2[1] + acc2[2] + acc2[3];
      c2 += __shfl_xor(c2, 16, 64);
      c2 += __shfl_xor(c2, 32, 64);
    }
    if ((lane >> 4) == 0) {              // lanes 0..15 hold full 16-row sums
      atomicAdd(&tvec[ct0 * 16 + lr], c0);
      atomicAdd(&tvec[(ct0 + 1) * 16 + lr], c1);
      if (nct == 3) atomicAdd(&tvec[(ct0 + 2) * 16 + lr], c2);
    }
  }
}

// colstats: term1 = sum (x-mu)^2/sigma; block 0 also sum(log sigma)
__device__ void colstats_body(const float* __restrict__ x,
                              const float* __restrict__ theta,
                              float* __restrict__ scalars, int cb) {
  int i0 = cb * CS_ROWS;
  const float* mu = theta + (size_t)D * K;
  const float* sg = mu + D;
  int dA = threadIdx.x * 4, dB = (threadIdx.x + 512) * 4;
  float4 muA = *reinterpret_cast<const float4*>(&mu[dA]);
  float4 sgA = *reinterpret_cast<const float4*>(&sg[dA]);
  float4 muB = *reinterpret_cast<const float4*>(&mu[dB]);
  float4 sgB = *reinterpret_cast<const float4*>(&sg[dB]);
  float4 ivA = {1.0f / sgA.x, 1.0f / sgA.y, 1.0f / sgA.z, 1.0f / sgA.w};
  float4 ivB = {1.0f / sgB.x, 1.0f / sgB.y, 1.0f / sgB.z, 1.0f / sgB.w};
  float t1 = 0.0f;
  for (int i = i0; i < i0 + CS_ROWS; ++i) {
    float4 a = *reinterpret_cast<const float4*>(&x[(size_t)i * D + dA]);
    float4 b = *reinterpret_cast<const float4*>(&x[(size_t)i * D + dB]);
    float ax = a.x - muA.x, ay = a.y - muA.y, az = a.z - muA.z, aw = a.w - muA.w;
    float bx = b.x - muB.x, by = b.y - muB.y, bz = b.z - muB.z, bw = b.w - muB.w;
    t1 += ax * ax * ivA.x + ay * ay * ivA.y + az * az * ivA.z + aw * aw * ivA.w;
    t1 += bx * bx * ivB.x + by * by * ivB.y + bz * bz * ivB.z + bw * bw * ivB.w;
  }
  float r = blockReduceSum512(t1);
  if (threadIdx.x == 0) atomicAdd(&scalars[1], r);
  if (cb == 0) {
    float lg = logf(sgA.x) + logf(sgA.y) + logf(sgA.z) + logf(sgA.w)
             + logf(sgB.x) + logf(sgB.y) + logf(sgB.z) + logf(sgB.w);
    float r2 = blockReduceSum512(lg);
    if (threadIdx.x == 0) atomicAdd(&scalars[0], r2);
  }
}

// mvec[c] = sum_d VbT[c][d] * mu[d]; 512 threads, 8 elems each
__device__ void mvec_body(const unsigned short* __restrict__ VbT,
                          const float* __restrict__ theta,
                          float* __restrict__ mvec, int c) {
  const float* mu = theta + (size_t)D * K;
  int d = threadIdx.x * 8;
  ushort4 u0 = *reinterpret_cast<const ushort4*>(&VbT[(size_t)c * D + d]);
  ushort4 u1 = *reinterpret_cast<const ushort4*>(&VbT[(size_t)c * D + d + 4]);
  float4 m0 = *reinterpret_cast<const float4*>(&mu[d]);
  float4 m1 = *reinterpret_cast<const float4*>(&mu[d + 4]);
  float a = bf2f(u0.x) * m0.x + bf2f(u0.y) * m0.y + bf2f(u0.z) * m0.z + bf2f(u0.w) * m0.w
          + bf2f(u1.x) * m1.x + bf2f(u1.y) * m1.y + bf2f(u1.z) * m1.z + bf2f(u1.w) * m1.w;
  float r = blockReduceSum512(a);
  if (threadIdx.x == 0) mvec[c] = r;
}

__global__ __launch_bounds__(512, 1) void k_par(const float* __restrict__ x,
                                                const float* __restrict__ theta,
                                                const unsigned short* __restrict__ VbT,
                                                unsigned short* __restrict__ Yb,
                                                const float* __restrict__ Mg,
                                                float* __restrict__ Gg,
                                                float* __restrict__ scalars,
                                                float* __restrict__ tvec,
                                                float* __restrict__ mvec) {
  __shared__ ParSh sh;
  int b = blockIdx.x;
  if (b == 0) {
    chol_body(sh.c, Mg, Gg, scalars);
  } else if (b <= GEMM_BLOCKS) {
    gemm_body(sh.g, x, VbT, Yb, tvec, b - 1);
  } else if (b <= GEMM_BLOCKS + CS_BLOCKS) {
    colstats_body(x, theta, scalars, b - 1 - GEMM_BLOCKS);
  } else {
    mvec_body(VbT, theta, mvec, b - 1 - GEMM_BLOCKS - CS_BLOCKS);
  }
}

// ---------------- Q += Yb^T Yb  (bf16 in, symmetry, row-split atomics) ----------------
#define SYRK_ZSPLIT 16
__global__ __launch_bounds__(256) void k_syrk(const unsigned short* __restrict__ Yb,
                                              float* __restrict__ Q) {
  int bj = blockIdx.x * 16, bk = blockIdx.y * 16;
  if (bk < bj) return;                   // symmetry (upper only; trace reads upper)
  __shared__ float Ya[64][17];
  __shared__ float Yc[64][17];
  int i0base = blockIdx.z * (NROWS / SYRK_ZSPLIT);
  int tid = threadIdx.x;
  int tj = tid & 15, tk = tid >> 4;
  int lr = tid >> 2, lc = (tid & 3) * 4;
  float acc = 0.0f;
  for (int i0 = i0base; i0 < i0base + NROWS / SYRK_ZSPLIT; i0 += 64) {
    ushort4 va = *reinterpret_cast<const ushort4*>(&Yb[(size_t)(i0 + lr) * NC + bj + lc]);
    ushort4 vc = *reinterpret_cast<const ushort4*>(&Yb[(size_t)(i0 + lr) * NC + bk + lc]);
    Ya[lr][lc + 0] = bf2f(va.x); Ya[lr][lc + 1] = bf2f(va.y);
    Ya[lr][lc + 2] = bf2f(va.z); Ya[lr][lc + 3] = bf2f(va.w);
    Yc[lr][lc + 0] = bf2f(vc.x); Yc[lr][lc + 1] = bf2f(vc.y);
    Yc[lr][lc + 2] = bf2f(vc.z); Yc[lr][lc + 3] = bf2f(vc.w);
    __syncthreads();
    #pragma unroll
    for (int ii = 0; ii < 64; ++ii) acc += Ya[ii][tj] * Yc[ii][tk];
    __syncthreads();
  }
  atomicAdd(&Q[(bj + tj) * QS + bk + tk], acc);
}

// ---------------- k_trace: tr(M^-1 S) via GT row-dots + final combine ----------------
__global__ __launch_bounds__(256) void k_trace(const float* __restrict__ Gg,
                                               const float* __restrict__ Qg,
                                               const float* __restrict__ tvec,
                                               const float* __restrict__ mvec,
                                               float* __restrict__ scalars,
                                               const int* __restrict__ fds,
                                               float* __restrict__ out) {
  int b = blockIdx.x;                    // 0..44 -> upper tile pair (tjT <= tkT)
  int tkT = (int)((sqrtf(8.0f * (float)b + 1.0f) - 1.0f) * 0.5f);
  while ((tkT + 1) * (tkT + 2) / 2 <= b) ++tkT;
  while (tkT * (tkT + 1) / 2 > b) --tkT;
  int tjT = b - tkT * (tkT + 1) / 2;
  int bj = tjT * 16, bk = tkT * 16;
  int tj = threadIdx.x & 15, tk = threadIdx.x >> 4;
  int j = bj + tj, k = bk + tk;
  float acc = 0.0f;
  if (j <= k && k < NP && j < KP && k < KP) {
    const float* gj = Gg + (size_t)j * NP;
    const float* gk = Gg + (size_t)k * NP;
    float h0 = 0.f, h1 = 0.f;
    #pragma unroll 4
    for (int i4 = 0; i4 < NP / 4; ++i4) {
      float4 a = *reinterpret_cast<const float4*>(gj + i4 * 4);
      float4 c = *reinterpret_cast<const float4*>(gk + i4 * 4);
      h0 += a.x * c.x + a.y * c.y;
      h1 += a.z * c.z + a.w * c.w;
    }
    float h = h0 + h1;
    float tlj = tvec[j], mlj = mvec[j], tlk = tvec[k], mlk = mvec[k];
    float S = Qg[j * QS + k] - tlj * mlk - mlj * tlk + (float)NROWS * mlj * mlk;
    acc = ((j == k) ? 1.0f : 2.0f) * h * S;
  }
  float r = blockReduceSum256(acc);
  if (threadIdx.x == 0) {
    atomicAdd(&scalars[3], r);
    __threadfence();
    unsigned old = atomicAdd(reinterpret_cast<unsigned int*>(scalars + 4), 1u);
    if (old == NTRACE - 1) {             // last block combines
      float tr = atomicAdd(&scalars[3], 0.0f);   // device-coherent read
      double sumlog  = (double)scalars[0];
      double term1   = (double)scalars[1];
      double logdetM = (double)scalars[2];
      double total = (double)NROWS * (double)D * LOG2PI
                   + (double)NROWS * (sumlog + logdetM)
                   + term1 - (double)tr;
      double scale = (double)fds[0] / (double)NROWS;
      out[0] = (float)(scale * (-0.5) * total);
    }
  }
}

// ---------------- launch ----------------
extern "C" void kernel_launch(void* const* d_in, const int* in_sizes, int n_in,
                              void* d_out, int out_size, void* d_ws, size_t ws_size,
                              hipStream_t stream) {
  const float* x     = (const float*)d_in[0];
  const float* theta = (const float*)d_in[1];
  const int*   fds   = (const int*)d_in[2];
  float* out = (float*)d_out;
  float* ws = (float*)d_ws;

  // zeroed region first: Q | tvec | scalars (contiguous)
  float* Q        = ws;                          // QS*QS = 20736
  float* tvec     = Q + QS * QS;                 // NC (atomic col sums)
  float* scalars  = tvec + NC;                   // 8
  unsigned short* Yb  = (unsigned short*)(scalars + 8);    // NROWS*NC bf16
  unsigned short* VbT = Yb + (size_t)NROWS * NC;           // NC*D bf16
  float* M        = (float*)(VbT + (size_t)NC * D);        // KP*MS
  float* mvec     = M + KP * MS;                 // NC
  float* Gg       = mvec + NC;                   // NP*NP (stores G^T)

  hipMemsetAsync(Q, 0, (size_t)(QS * QS + NC + 8) * sizeof(float), stream);

  k_prep <<<dim3(D / PD), 256, 0, stream>>>(theta, VbT);
  k_M    <<<dim3(KP, KP), 256, 0, stream>>>(theta, VbT, M);
  k_par  <<<dim3(1 + GEMM_BLOCKS + CS_BLOCKS + KP), 512, 0, stream>>>(
             x, theta, VbT, Yb, M, Gg, scalars, tvec, mvec);
  k_syrk <<<dim3(QS / 16, QS / 16, SYRK_ZSPLIT), 256, 0, stream>>>(Yb, Q);
  k_trace<<<dim3(NTRACE), 256, 0, stream>>>(Gg, Q, tvec, mvec, scalars, fds, out);
}